// Round 1
// baseline (777.093 us; speedup 1.0000x reference)
//
#include <hip/hip_runtime.h>
#include <hip/hip_bf16.h>

#define B_    2
#define T_    2048
#define C_    2048
#define NH_   16
#define KVH_  4
#define HD_   128
#define QKV_  3072
#define M_    4096

typedef float  floatx4 __attribute__((ext_vector_type(4)));
typedef __bf16 bf16x8  __attribute__((ext_vector_type(8)));
typedef __bf16 bf16x4  __attribute__((ext_vector_type(4)));
typedef __bf16 bf16x2  __attribute__((ext_vector_type(2)));

// ---------------- fp32 -> bf16 conversion (memory-bound) ----------------
__global__ __launch_bounds__(256) void cvt_bf16(const float* __restrict__ src,
                                                __bf16* __restrict__ dst, int n4) {
  int i = blockIdx.x * blockDim.x + threadIdx.x;
  if (i < n4) {
    float4 f = ((const float4*)src)[i];
    bf16x4 o = { (__bf16)f.x, (__bf16)f.y, (__bf16)f.z, (__bf16)f.w };
    ((bf16x4*)dst)[i] = o;
  }
}

// ---------------- C = A[M][K] * B[N][K]^T, fp32 out ----------------
// 128x128 block tile, 4 waves (2x2), each wave 64x64 = 4x4 MFMA 16x16x32.
__global__ __launch_bounds__(256) void gemm_bt(const __bf16* __restrict__ A,
                                               const __bf16* __restrict__ Bm,
                                               float* __restrict__ Cc,
                                               int N, int K) {
  // +8 bf16 pad per 32-elem row -> 80B stride -> max 2-way bank aliasing (free)
  __shared__ __align__(16) __bf16 As[128 * 40];
  __shared__ __align__(16) __bf16 Bs[128 * 40];
  const int tid  = threadIdx.x;
  const int wid  = tid >> 6, lane = tid & 63, quad = lane >> 4, r16 = lane & 15;
  const int bm   = blockIdx.y * 128, bn = blockIdx.x * 128;
  const int wm   = (wid >> 1) * 64, wn = (wid & 1) * 64;
  const int srow = tid >> 2, scol = (tid & 3) * 8;

  floatx4 acc[4][4];
  #pragma unroll
  for (int i = 0; i < 4; i++) {
    #pragma unroll
    for (int j = 0; j < 4; j++) acc[i][j] = (floatx4){0.f, 0.f, 0.f, 0.f};
  }

  for (int k0 = 0; k0 < K; k0 += 32) {
    *(bf16x8*)&As[srow * 40 + scol]        = *(const bf16x8*)&A[(size_t)(bm + srow) * K + k0 + scol];
    *(bf16x8*)&As[(srow + 64) * 40 + scol] = *(const bf16x8*)&A[(size_t)(bm + srow + 64) * K + k0 + scol];
    *(bf16x8*)&Bs[srow * 40 + scol]        = *(const bf16x8*)&Bm[(size_t)(bn + srow) * K + k0 + scol];
    *(bf16x8*)&Bs[(srow + 64) * 40 + scol] = *(const bf16x8*)&Bm[(size_t)(bn + srow + 64) * K + k0 + scol];
    __syncthreads();

    bf16x8 af[4], bfr[4];
    #pragma unroll
    for (int i = 0; i < 4; i++) af[i]  = *(const bf16x8*)&As[(wm + i * 16 + r16) * 40 + quad * 8];
    #pragma unroll
    for (int j = 0; j < 4; j++) bfr[j] = *(const bf16x8*)&Bs[(wn + j * 16 + r16) * 40 + quad * 8];

    #pragma unroll
    for (int i = 0; i < 4; i++) {
      #pragma unroll
      for (int j = 0; j < 4; j++)
        acc[i][j] = __builtin_amdgcn_mfma_f32_16x16x32_bf16(af[i], bfr[j], acc[i][j], 0, 0, 0);
    }
    __syncthreads();
  }

  #pragma unroll
  for (int i = 0; i < 4; i++) {
    #pragma unroll
    for (int reg = 0; reg < 4; reg++) {
      int row = bm + wm + i * 16 + quad * 4 + reg;
      float* crow = Cc + (size_t)row * N + bn + wn;
      #pragma unroll
      for (int j = 0; j < 4; j++) crow[j * 16 + r16] = acc[i][j][reg];
    }
  }
}

// ---------------- RoPE + RMSNorm (+ V transpose), one wave per (b,t) row ----------------
__global__ __launch_bounds__(256) void rope_norm(const float* __restrict__ qkv,
                                                 const float* __restrict__ qw,
                                                 const float* __restrict__ kw,
                                                 const float* __restrict__ fc,
                                                 const float* __restrict__ fs,
                                                 __bf16* __restrict__ qn,
                                                 __bf16* __restrict__ kn,
                                                 __bf16* __restrict__ vT) {
  const int tid  = threadIdx.x;
  const int wid  = tid >> 6, lane = tid & 63;   // lane = rope pair index 0..63
  const int row  = blockIdx.x * 4 + wid;        // b*T + t
  const int b    = row >> 11, t = row & (T_ - 1);
  const float cs = fc[t * 64 + lane], sn = fs[t * 64 + lane];
  const float* base = qkv + (size_t)row * QKV_;

  #pragma unroll 2
  for (int h = 0; h < NH_; h++) {
    float2 ab = *(const float2*)(base + h * HD_ + 2 * lane);
    float oa = ab.x * cs - ab.y * sn;
    float ob = ab.x * sn + ab.y * cs;
    float ss = oa * oa + ob * ob;
    #pragma unroll
    for (int off = 32; off; off >>= 1) ss += __shfl_xor(ss, off);
    float rinv = rsqrtf(ss * (1.0f / HD_) + 1e-6f);
    bf16x2 o = { (__bf16)(oa * rinv * qw[2 * lane]), (__bf16)(ob * rinv * qw[2 * lane + 1]) };
    *(bf16x2*)&qn[(size_t)((b * NH_ + h) * T_ + t) * HD_ + 2 * lane] = o;
  }
  #pragma unroll 2
  for (int h = 0; h < KVH_; h++) {
    float2 ab = *(const float2*)(base + C_ + h * HD_ + 2 * lane);
    float oa = ab.x * cs - ab.y * sn;
    float ob = ab.x * sn + ab.y * cs;
    float ss = oa * oa + ob * ob;
    #pragma unroll
    for (int off = 32; off; off >>= 1) ss += __shfl_xor(ss, off);
    float rinv = rsqrtf(ss * (1.0f / HD_) + 1e-6f);
    bf16x2 o = { (__bf16)(oa * rinv * kw[2 * lane]), (__bf16)(ob * rinv * kw[2 * lane + 1]) };
    *(bf16x2*)&kn[(size_t)((b * KVH_ + h) * T_ + t) * HD_ + 2 * lane] = o;
  }
  #pragma unroll 2
  for (int h = 0; h < KVH_; h++) {
    float2 ab = *(const float2*)(base + C_ + KVH_ * HD_ + h * HD_ + 2 * lane);
    size_t vb = (size_t)(b * KVH_ + h) * HD_;
    vT[(vb + 2 * lane) * T_ + t]     = (__bf16)ab.x;   // scattered 2B writes (round-1 tax)
    vT[(vb + 2 * lane + 1) * T_ + t] = (__bf16)ab.y;
  }
}

// ---------------- causal flash attention: 1 wave = 16 Q rows ----------------
__global__ __launch_bounds__(256) void flash(const __bf16* __restrict__ q,
                                             const __bf16* __restrict__ k,
                                             const __bf16* __restrict__ vT,
                                             __bf16* __restrict__ y) {
  __shared__ __align__(16) __bf16 P[4][16 * 40];  // wave-private P scratch (C->A layout)
  const int tid = threadIdx.x;
  const int wid = tid >> 6, lane = tid & 63, quad = lane >> 4, r16 = lane & 15;
  const int h = blockIdx.y, b = blockIdx.z;
  const int hk = h >> 2;                          // GQA: 4 q-heads per kv-head
  const int r0 = blockIdx.x * 64 + wid * 16;

  const __bf16* qrow = q + ((size_t)(b * NH_ + h) * T_ + r0 + r16) * HD_;
  bf16x8 qf[4];
  #pragma unroll
  for (int kb = 0; kb < 4; kb++) qf[kb] = *(const bf16x8*)&qrow[kb * 32 + quad * 8];

  floatx4 o[8];
  #pragma unroll
  for (int j = 0; j < 8; j++) o[j] = (floatx4){0.f, 0.f, 0.f, 0.f};
  const float NEG = -__builtin_inff();
  float m_r[4] = {NEG, NEG, NEG, NEG};
  float l_r[4] = {0.f, 0.f, 0.f, 0.f};

  const __bf16* kbase = k  + (size_t)(b * KVH_ + hk) * T_ * HD_;
  const __bf16* vbase = vT + (size_t)(b * KVH_ + hk) * HD_ * T_;
  __bf16* Pw = P[wid];
  const float sc = 0.08838834764831845f;  // 1/sqrt(128)

  for (int kt0 = 0; kt0 <= r0 + 15; kt0 += 32) {
    floatx4 s0 = {0.f, 0.f, 0.f, 0.f}, s1 = {0.f, 0.f, 0.f, 0.f};
    const __bf16* kb0 = kbase + (size_t)(kt0 + r16) * HD_;
    const __bf16* kb1 = kbase + (size_t)(kt0 + 16 + r16) * HD_;
    #pragma unroll
    for (int kb = 0; kb < 4; kb++) {
      bf16x8 kf0 = *(const bf16x8*)&kb0[kb * 32 + quad * 8];
      bf16x8 kf1 = *(const bf16x8*)&kb1[kb * 32 + quad * 8];
      s0 = __builtin_amdgcn_mfma_f32_16x16x32_bf16(qf[kb], kf0, s0, 0, 0, 0);
      s1 = __builtin_amdgcn_mfma_f32_16x16x32_bf16(qf[kb], kf1, s1, 0, 0, 0);
    }
    #pragma unroll
    for (int reg = 0; reg < 4; reg++) {
      int rowq = r0 + quad * 4 + reg;
      float v0 = (kt0 + r16      <= rowq) ? s0[reg] * sc : NEG;
      float v1 = (kt0 + 16 + r16 <= rowq) ? s1[reg] * sc : NEG;
      float mx = fmaxf(v0, v1);
      #pragma unroll
      for (int off = 8; off; off >>= 1) mx = fmaxf(mx, __shfl_xor(mx, off));
      float mnew  = fmaxf(m_r[reg], mx);
      float alpha = __expf(m_r[reg] - mnew);
      float p0 = __expf(v0 - mnew);
      float p1 = __expf(v1 - mnew);
      float rs = p0 + p1;
      #pragma unroll
      for (int off = 8; off; off >>= 1) rs += __shfl_xor(rs, off);
      l_r[reg] = l_r[reg] * alpha + rs;
      m_r[reg] = mnew;
      #pragma unroll
      for (int j = 0; j < 8; j++) o[j][reg] *= alpha;
      Pw[(quad * 4 + reg) * 40 + r16]      = (__bf16)p0;
      Pw[(quad * 4 + reg) * 40 + 16 + r16] = (__bf16)p1;
    }
    __asm__ volatile("" ::: "memory");  // keep DS writes before DS read (same-wave, in-order HW)
    bf16x8 pf = *(const bf16x8*)&Pw[r16 * 40 + quad * 8];
    #pragma unroll
    for (int j = 0; j < 8; j++) {
      bf16x8 vf = *(const bf16x8*)&vbase[(size_t)(j * 16 + r16) * T_ + kt0 + quad * 8];
      o[j] = __builtin_amdgcn_mfma_f32_16x16x32_bf16(pf, vf, o[j], 0, 0, 0);
    }
  }

  #pragma unroll
  for (int reg = 0; reg < 4; reg++) {
    int trow = r0 + quad * 4 + reg;
    float inv = 1.0f / l_r[reg];
    __bf16* yr = y + ((size_t)(b * T_) + trow) * C_ + h * HD_;
    #pragma unroll
    for (int j = 0; j < 8; j++) yr[j * 16 + r16] = (__bf16)(o[j][reg] * inv);
  }
}

extern "C" void kernel_launch(void* const* d_in, const int* in_sizes, int n_in,
                              void* d_out, int out_size, void* d_ws, size_t ws_size,
                              hipStream_t stream) {
  const float* x     = (const float*)d_in[0];
  const float* wqkv  = (const float*)d_in[1];
  const float* wproj = (const float*)d_in[2];
  const float* qw    = (const float*)d_in[3];
  const float* kw    = (const float*)d_in[4];
  const float* fc    = (const float*)d_in[5];
  const float* fs    = (const float*)d_in[6];
  float* out = (float*)d_out;

  char* w = (char*)d_ws;
  __bf16* xb     = (__bf16*)w; w += (size_t)M_ * C_ * 2;
  __bf16* wqkvb  = (__bf16*)w; w += (size_t)QKV_ * C_ * 2;
  __bf16* wprojb = (__bf16*)w; w += (size_t)C_ * C_ * 2;
  float*  qkv    = (float*)w;  w += (size_t)M_ * QKV_ * 4;
  __bf16* qn     = (__bf16*)w; w += (size_t)B_ * NH_ * T_ * HD_ * 2;
  __bf16* kn     = (__bf16*)w; w += (size_t)B_ * KVH_ * T_ * HD_ * 2;
  __bf16* vT     = (__bf16*)w; w += (size_t)B_ * KVH_ * T_ * HD_ * 2;
  __bf16* ybf    = (__bf16*)w; w += (size_t)M_ * C_ * 2;

  cvt_bf16<<<M_ * C_ / 4 / 256, 256, 0, stream>>>(x, xb, M_ * C_ / 4);
  cvt_bf16<<<QKV_ * C_ / 4 / 256, 256, 0, stream>>>(wqkv, wqkvb, QKV_ * C_ / 4);
  cvt_bf16<<<C_ * C_ / 4 / 256, 256, 0, stream>>>(wproj, wprojb, C_ * C_ / 4);

  gemm_bt<<<dim3(QKV_ / 128, M_ / 128), 256, 0, stream>>>(xb, wqkvb, qkv, QKV_, C_);
  rope_norm<<<M_ / 4, 256, 0, stream>>>(qkv, qw, kw, fc, fs, qn, kn, vT);
  flash<<<dim3(T_ / 64, NH_, B_), 256, 0, stream>>>(qn, kn, vT, ybf);
  gemm_bt<<<dim3(C_ / 128, M_ / 128), 256, 0, stream>>>(ybf, wprojb, out, C_, C_);
}

// Round 2
// 435.985 us; speedup vs baseline: 1.7824x; 1.7824x over previous
//
#include <hip/hip_runtime.h>
#include <hip/hip_bf16.h>

#define B_    2
#define T_    2048
#define C_    2048
#define NH_   16
#define KVH_  4
#define HD_   128
#define QKV_  3072
#define M_    4096

typedef float  floatx4 __attribute__((ext_vector_type(4)));
typedef __bf16 bf16x8  __attribute__((ext_vector_type(8)));
typedef __bf16 bf16x4  __attribute__((ext_vector_type(4)));
typedef __bf16 bf16x2  __attribute__((ext_vector_type(2)));

typedef const __attribute__((address_space(1))) void* gas_t;
typedef __attribute__((address_space(3))) void*       las_t;
__device__ __forceinline__ void gl_lds16(const void* g, void* l) {
  __builtin_amdgcn_global_load_lds((gas_t)g, (las_t)l, 16, 0, 0);
}

// ---------------- fp32 -> bf16 conversion (memory-bound) ----------------
__global__ __launch_bounds__(256) void cvt_bf16(const float* __restrict__ src,
                                                __bf16* __restrict__ dst, int n4) {
  int i = blockIdx.x * blockDim.x + threadIdx.x;
  if (i < n4) {
    float4 f = ((const float4*)src)[i];
    bf16x4 o = { (__bf16)f.x, (__bf16)f.y, (__bf16)f.z, (__bf16)f.w };
    ((bf16x4*)dst)[i] = o;
  }
}

// ---------------- C = A[M][K] * B[N][K]^T, fp32 out (m97 structure) ----------------
// 128x128 block tile, 4 waves (2x2), global_load_lds width-16 staging, no LDS pad.
__global__ __launch_bounds__(256) void gemm_bt(const __bf16* __restrict__ A,
                                               const __bf16* __restrict__ Bm,
                                               float* __restrict__ Cc,
                                               int N, int K) {
  __shared__ __align__(16) __bf16 As[128 * 32];
  __shared__ __align__(16) __bf16 Bs[128 * 32];
  const int tid  = threadIdx.x;
  const int wid  = tid >> 6, lane = tid & 63, quad = lane >> 4, r16 = lane & 15;
  const int bm   = blockIdx.y * 128, bn = blockIdx.x * 128;
  const int wm   = (wid >> 1) * 64, wn = (wid & 1) * 64;
  // lane l of wave w stages row w*16 + l/4, cols (l&3)*8 -> LDS linear = base + l*16B
  const int srow = wid * 16 + (lane >> 2);
  const int scol = (lane & 3) * 8;
  const __bf16* aptr = A  + (size_t)(bm + srow) * K + scol;
  const __bf16* bptr = Bm + (size_t)(bn + srow) * K + scol;
  __bf16* ldsA0 = &As[wid * 512];
  __bf16* ldsA1 = &As[2048 + wid * 512];
  __bf16* ldsB0 = &Bs[wid * 512];
  __bf16* ldsB1 = &Bs[2048 + wid * 512];
  const size_t rowskip = (size_t)64 * K;

  floatx4 acc[4][4];
  #pragma unroll
  for (int i = 0; i < 4; i++)
    #pragma unroll
    for (int j = 0; j < 4; j++) acc[i][j] = (floatx4){0.f, 0.f, 0.f, 0.f};

  for (int k0 = 0; k0 < K; k0 += 32) {
    gl_lds16(aptr + k0,           ldsA0);
    gl_lds16(aptr + rowskip + k0, ldsA1);
    gl_lds16(bptr + k0,           ldsB0);
    gl_lds16(bptr + rowskip + k0, ldsB1);
    __syncthreads();

    bf16x8 af[4], bfr[4];
    #pragma unroll
    for (int i = 0; i < 4; i++) af[i]  = *(const bf16x8*)&As[(wm + i * 16 + r16) * 32 + quad * 8];
    #pragma unroll
    for (int j = 0; j < 4; j++) bfr[j] = *(const bf16x8*)&Bs[(wn + j * 16 + r16) * 32 + quad * 8];

    #pragma unroll
    for (int i = 0; i < 4; i++)
      #pragma unroll
      for (int j = 0; j < 4; j++)
        acc[i][j] = __builtin_amdgcn_mfma_f32_16x16x32_bf16(af[i], bfr[j], acc[i][j], 0, 0, 0);
    __syncthreads();
  }

  #pragma unroll
  for (int i = 0; i < 4; i++) {
    #pragma unroll
    for (int reg = 0; reg < 4; reg++) {
      int row = bm + wm + i * 16 + quad * 4 + reg;
      float* crow = Cc + (size_t)row * N + bn + wn;
      #pragma unroll
      for (int j = 0; j < 4; j++) crow[j * 16 + r16] = acc[i][j][reg];
    }
  }
}

// ---------------- RoPE + RMSNorm (+ V transpose), one wave per (b,t) row ----------------
__global__ __launch_bounds__(256) void rope_norm(const float* __restrict__ qkv,
                                                 const float* __restrict__ qw,
                                                 const float* __restrict__ kw,
                                                 const float* __restrict__ fc,
                                                 const float* __restrict__ fs,
                                                 __bf16* __restrict__ qn,
                                                 __bf16* __restrict__ kn,
                                                 __bf16* __restrict__ vT) {
  const int tid  = threadIdx.x;
  const int wid  = tid >> 6, lane = tid & 63;
  const int row  = blockIdx.x * 4 + wid;        // b*T + t
  const int b    = row >> 11, t = row & (T_ - 1);
  const float cs = fc[t * 64 + lane], sn = fs[t * 64 + lane];
  const float* base = qkv + (size_t)row * QKV_;

  #pragma unroll 2
  for (int h = 0; h < NH_; h++) {
    float2 ab = *(const float2*)(base + h * HD_ + 2 * lane);
    float oa = ab.x * cs - ab.y * sn;
    float ob = ab.x * sn + ab.y * cs;
    float ss = oa * oa + ob * ob;
    #pragma unroll
    for (int off = 32; off; off >>= 1) ss += __shfl_xor(ss, off);
    float rinv = rsqrtf(ss * (1.0f / HD_) + 1e-6f);
    bf16x2 o = { (__bf16)(oa * rinv * qw[2 * lane]), (__bf16)(ob * rinv * qw[2 * lane + 1]) };
    *(bf16x2*)&qn[(size_t)((b * NH_ + h) * T_ + t) * HD_ + 2 * lane] = o;
  }
  #pragma unroll 2
  for (int h = 0; h < KVH_; h++) {
    float2 ab = *(const float2*)(base + C_ + h * HD_ + 2 * lane);
    float oa = ab.x * cs - ab.y * sn;
    float ob = ab.x * sn + ab.y * cs;
    float ss = oa * oa + ob * ob;
    #pragma unroll
    for (int off = 32; off; off >>= 1) ss += __shfl_xor(ss, off);
    float rinv = rsqrtf(ss * (1.0f / HD_) + 1e-6f);
    bf16x2 o = { (__bf16)(oa * rinv * kw[2 * lane]), (__bf16)(ob * rinv * kw[2 * lane + 1]) };
    *(bf16x2*)&kn[(size_t)((b * KVH_ + h) * T_ + t) * HD_ + 2 * lane] = o;
  }
  #pragma unroll 2
  for (int h = 0; h < KVH_; h++) {
    float2 ab = *(const float2*)(base + C_ + KVH_ * HD_ + h * HD_ + 2 * lane);
    size_t vb = (size_t)(b * KVH_ + h) * HD_;
    vT[(vb + 2 * lane) * T_ + t]     = (__bf16)ab.x;   // scattered 2B writes (fix later)
    vT[(vb + 2 * lane + 1) * T_ + t] = (__bf16)ab.y;
  }
}

// ---------------- causal flash attention ----------------
// Block = 64 Q rows of one head, 4 waves x 16 rows. K-tile = 64, staged in LDS
// shared by all 4 waves (same kv-head). Row-sum via MFMA-with-ones (no shuffle sum).
__global__ __launch_bounds__(256) void flash(const __bf16* __restrict__ q,
                                             const __bf16* __restrict__ k,
                                             const __bf16* __restrict__ vT,
                                             __bf16* __restrict__ y) {
  __shared__ __align__(16) __bf16 Ks[64 * 136];   // [kt][d], +8 pad
  __shared__ __align__(16) __bf16 Vs[128 * 72];   // [d][kt], +8 pad
  __shared__ __align__(16) __bf16 Ps[4][16 * 72]; // per-wave P scratch, +8 pad
  const int tid = threadIdx.x;
  const int wid = tid >> 6, lane = tid & 63, quad = lane >> 4, r16 = lane & 15;
  const int h = blockIdx.y, b = blockIdx.z;
  const int hk = h >> 2;
  const int blk = gridDim.x - 1 - blockIdx.x;     // heavy (long-loop) blocks first
  const int r0 = blk * 64 + wid * 16;

  const __bf16* qrow = q + ((size_t)(b * NH_ + h) * T_ + r0 + r16) * HD_;
  bf16x8 qf[4];
  #pragma unroll
  for (int kb = 0; kb < 4; kb++) qf[kb] = *(const bf16x8*)&qrow[kb * 32 + quad * 8];

  floatx4 o[8], ol;
  #pragma unroll
  for (int j = 0; j < 8; j++) o[j] = (floatx4){0.f, 0.f, 0.f, 0.f};
  ol = (floatx4){0.f, 0.f, 0.f, 0.f};
  const float NEG = -__builtin_inff();
  float m_r[4] = {NEG, NEG, NEG, NEG};

  const __bf16* kbase = k  + (size_t)(b * KVH_ + hk) * T_ * HD_;
  const __bf16* vbase = vT + (size_t)(b * KVH_ + hk) * HD_ * T_;
  __bf16* Pw = Ps[wid];
  const float sc = 0.08838834764831845f;  // 1/sqrt(128)

  bf16x8 ones;
  #pragma unroll
  for (int i = 0; i < 8; i++) ones[i] = (__bf16)1.0f;

  const int srowK = tid >> 4, scolK = (tid & 15) * 8;
  const int srowV = tid >> 3, scolV = (tid & 7) * 8;

  const int ntiles = blk + 1;
  for (int it = 0; it < ntiles; ++it) {
    const int kt0 = it * 64;
    __syncthreads();
    #pragma unroll
    for (int p2 = 0; p2 < 4; p2++) {
      *(bf16x8*)&Ks[(p2 * 16 + srowK) * 136 + scolK] =
          *(const bf16x8*)&kbase[(size_t)(kt0 + p2 * 16 + srowK) * HD_ + scolK];
      *(bf16x8*)&Vs[(p2 * 32 + srowV) * 72 + scolV] =
          *(const bf16x8*)&vbase[(size_t)(p2 * 32 + srowV) * T_ + kt0 + scolV];
    }
    __syncthreads();

    floatx4 s[4];
    #pragma unroll
    for (int cb = 0; cb < 4; cb++) s[cb] = (floatx4){0.f, 0.f, 0.f, 0.f};
    #pragma unroll
    for (int kb = 0; kb < 4; kb++) {
      #pragma unroll
      for (int cb = 0; cb < 4; cb++) {
        bf16x8 kf = *(const bf16x8*)&Ks[(cb * 16 + r16) * 136 + kb * 32 + quad * 8];
        s[cb] = __builtin_amdgcn_mfma_f32_16x16x32_bf16(qf[kb], kf, s[cb], 0, 0, 0);
      }
    }

    const bool last = (it == ntiles - 1);
    float alpha[4];
    #pragma unroll
    for (int reg = 0; reg < 4; reg++) {
      const int rowq = r0 + quad * 4 + reg;
      float v0 = s[0][reg] * sc, v1 = s[1][reg] * sc, v2 = s[2][reg] * sc, v3 = s[3][reg] * sc;
      if (last) {
        if (kt0 +      r16 > rowq) v0 = NEG;
        if (kt0 + 16 + r16 > rowq) v1 = NEG;
        if (kt0 + 32 + r16 > rowq) v2 = NEG;
        if (kt0 + 48 + r16 > rowq) v3 = NEG;
      }
      float mx = fmaxf(fmaxf(v0, v1), fmaxf(v2, v3));
      #pragma unroll
      for (int off = 8; off; off >>= 1) mx = fmaxf(mx, __shfl_xor(mx, off));
      float mnew = fmaxf(m_r[reg], mx);
      alpha[reg] = __expf(m_r[reg] - mnew);
      m_r[reg] = mnew;
      Pw[(quad * 4 + reg) * 72 +      r16] = (__bf16)__expf(v0 - mnew);
      Pw[(quad * 4 + reg) * 72 + 16 + r16] = (__bf16)__expf(v1 - mnew);
      Pw[(quad * 4 + reg) * 72 + 32 + r16] = (__bf16)__expf(v2 - mnew);
      Pw[(quad * 4 + reg) * 72 + 48 + r16] = (__bf16)__expf(v3 - mnew);
    }
    #pragma unroll
    for (int reg = 0; reg < 4; reg++) {
      ol[reg] *= alpha[reg];
      #pragma unroll
      for (int j = 0; j < 8; j++) o[j][reg] *= alpha[reg];
    }
    __asm__ volatile("" ::: "memory");  // keep wave-private DS writes before DS reads
    bf16x8 pf0 = *(const bf16x8*)&Pw[r16 * 72 + quad * 8];
    bf16x8 pf1 = *(const bf16x8*)&Pw[r16 * 72 + 32 + quad * 8];
    ol = __builtin_amdgcn_mfma_f32_16x16x32_bf16(pf0, ones, ol, 0, 0, 0);
    ol = __builtin_amdgcn_mfma_f32_16x16x32_bf16(pf1, ones, ol, 0, 0, 0);
    #pragma unroll
    for (int j = 0; j < 8; j++) {
      bf16x8 vf0 = *(const bf16x8*)&Vs[(j * 16 + r16) * 72 + quad * 8];
      bf16x8 vf1 = *(const bf16x8*)&Vs[(j * 16 + r16) * 72 + 32 + quad * 8];
      o[j] = __builtin_amdgcn_mfma_f32_16x16x32_bf16(pf0, vf0, o[j], 0, 0, 0);
      o[j] = __builtin_amdgcn_mfma_f32_16x16x32_bf16(pf1, vf1, o[j], 0, 0, 0);
    }
  }

  #pragma unroll
  for (int reg = 0; reg < 4; reg++) {
    int trow = r0 + quad * 4 + reg;
    float inv = 1.0f / ol[reg];  // rowsum identical across all 16 lanes (MFMA ones-trick)
    __bf16* yr = y + ((size_t)(b * T_) + trow) * C_ + h * HD_;
    #pragma unroll
    for (int j = 0; j < 8; j++) yr[j * 16 + r16] = (__bf16)(o[j][reg] * inv);
  }
}

extern "C" void kernel_launch(void* const* d_in, const int* in_sizes, int n_in,
                              void* d_out, int out_size, void* d_ws, size_t ws_size,
                              hipStream_t stream) {
  const float* x     = (const float*)d_in[0];
  const float* wqkv  = (const float*)d_in[1];
  const float* wproj = (const float*)d_in[2];
  const float* qw    = (const float*)d_in[3];
  const float* kw    = (const float*)d_in[4];
  const float* fc    = (const float*)d_in[5];
  const float* fs    = (const float*)d_in[6];
  float* out = (float*)d_out;

  char* w = (char*)d_ws;
  __bf16* xb     = (__bf16*)w; w += (size_t)M_ * C_ * 2;
  __bf16* wqkvb  = (__bf16*)w; w += (size_t)QKV_ * C_ * 2;
  __bf16* wprojb = (__bf16*)w; w += (size_t)C_ * C_ * 2;
  float*  qkv    = (float*)w;  w += (size_t)M_ * QKV_ * 4;
  __bf16* qn     = (__bf16*)w; w += (size_t)B_ * NH_ * T_ * HD_ * 2;
  __bf16* kn     = (__bf16*)w; w += (size_t)B_ * KVH_ * T_ * HD_ * 2;
  __bf16* vT     = (__bf16*)w; w += (size_t)B_ * KVH_ * T_ * HD_ * 2;
  __bf16* ybf    = (__bf16*)w; w += (size_t)M_ * C_ * 2;

  cvt_bf16<<<M_ * C_ / 4 / 256, 256, 0, stream>>>(x, xb, M_ * C_ / 4);
  cvt_bf16<<<QKV_ * C_ / 4 / 256, 256, 0, stream>>>(wqkv, wqkvb, QKV_ * C_ / 4);
  cvt_bf16<<<C_ * C_ / 4 / 256, 256, 0, stream>>>(wproj, wprojb, C_ * C_ / 4);

  gemm_bt<<<dim3(QKV_ / 128, M_ / 128), 256, 0, stream>>>(xb, wqkvb, qkv, QKV_, C_);
  rope_norm<<<M_ / 4, 256, 0, stream>>>(qkv, qw, kw, fc, fs, qn, kn, vT);
  flash<<<dim3(T_ / 64, NH_, B_), 256, 0, stream>>>(qn, kn, vT, ybf);
  gemm_bt<<<dim3(C_ / 128, M_ / 128), 256, 0, stream>>>(ybf, wprojb, out, C_, C_);
}

// Round 3
// 362.099 us; speedup vs baseline: 2.1461x; 1.2041x over previous
//
#include <hip/hip_runtime.h>
#include <hip/hip_bf16.h>

#define B_    2
#define T_    2048
#define C_    2048
#define NH_   16
#define KVH_  4
#define HD_   128
#define QKV_  3072
#define M_    4096

typedef float  floatx4 __attribute__((ext_vector_type(4)));
typedef __bf16 bf16x8  __attribute__((ext_vector_type(8)));
typedef __bf16 bf16x4  __attribute__((ext_vector_type(4)));
typedef __bf16 bf16x2  __attribute__((ext_vector_type(2)));

typedef const __attribute__((address_space(1))) void* gas_t;
typedef __attribute__((address_space(3))) void*       las_t;
__device__ __forceinline__ void gl_lds16(const void* g, void* l) {
  __builtin_amdgcn_global_load_lds((gas_t)g, (las_t)l, 16, 0, 0);
}

// ---------------- fp32 -> bf16 conversion (memory-bound) ----------------
__global__ __launch_bounds__(256) void cvt_bf16(const float* __restrict__ src,
                                                __bf16* __restrict__ dst, int n4) {
  int i = blockIdx.x * blockDim.x + threadIdx.x;
  if (i < n4) {
    float4 f = ((const float4*)src)[i];
    bf16x4 o = { (__bf16)f.x, (__bf16)f.y, (__bf16)f.z, (__bf16)f.w };
    ((bf16x4*)dst)[i] = o;
  }
}

// ---------------- C = A[M][K] * B[N][K]^T, fp32 out (m97 structure) ----------------
__global__ __launch_bounds__(256) void gemm_bt(const __bf16* __restrict__ A,
                                               const __bf16* __restrict__ Bm,
                                               float* __restrict__ Cc,
                                               int N, int K) {
  __shared__ __align__(16) __bf16 As[128 * 32];
  __shared__ __align__(16) __bf16 Bs[128 * 32];
  const int tid  = threadIdx.x;
  const int wid  = tid >> 6, lane = tid & 63, quad = lane >> 4, r16 = lane & 15;
  const int bm   = blockIdx.y * 128, bn = blockIdx.x * 128;
  const int wm   = (wid >> 1) * 64, wn = (wid & 1) * 64;
  const int srow = wid * 16 + (lane >> 2);
  const int scol = (lane & 3) * 8;
  const __bf16* aptr = A  + (size_t)(bm + srow) * K + scol;
  const __bf16* bptr = Bm + (size_t)(bn + srow) * K + scol;
  __bf16* ldsA0 = &As[wid * 512];
  __bf16* ldsA1 = &As[2048 + wid * 512];
  __bf16* ldsB0 = &Bs[wid * 512];
  __bf16* ldsB1 = &Bs[2048 + wid * 512];
  const size_t rowskip = (size_t)64 * K;

  floatx4 acc[4][4];
  #pragma unroll
  for (int i = 0; i < 4; i++)
    #pragma unroll
    for (int j = 0; j < 4; j++) acc[i][j] = (floatx4){0.f, 0.f, 0.f, 0.f};

  for (int k0 = 0; k0 < K; k0 += 32) {
    gl_lds16(aptr + k0,           ldsA0);
    gl_lds16(aptr + rowskip + k0, ldsA1);
    gl_lds16(bptr + k0,           ldsB0);
    gl_lds16(bptr + rowskip + k0, ldsB1);
    __syncthreads();

    bf16x8 af[4], bfr[4];
    #pragma unroll
    for (int i = 0; i < 4; i++) af[i]  = *(const bf16x8*)&As[(wm + i * 16 + r16) * 32 + quad * 8];
    #pragma unroll
    for (int j = 0; j < 4; j++) bfr[j] = *(const bf16x8*)&Bs[(wn + j * 16 + r16) * 32 + quad * 8];

    #pragma unroll
    for (int i = 0; i < 4; i++)
      #pragma unroll
      for (int j = 0; j < 4; j++)
        acc[i][j] = __builtin_amdgcn_mfma_f32_16x16x32_bf16(af[i], bfr[j], acc[i][j], 0, 0, 0);
    __syncthreads();
  }

  #pragma unroll
  for (int i = 0; i < 4; i++) {
    #pragma unroll
    for (int reg = 0; reg < 4; reg++) {
      int row = bm + wm + i * 16 + quad * 4 + reg;
      float* crow = Cc + (size_t)row * N + bn + wn;
      #pragma unroll
      for (int j = 0; j < 4; j++) crow[j * 16 + r16] = acc[i][j][reg];
    }
  }
}

// ---------------- RoPE + RMSNorm, one wave per (b,t) row ----------------
__global__ __launch_bounds__(256) void rope_norm(const float* __restrict__ qkv,
                                                 const float* __restrict__ qw,
                                                 const float* __restrict__ kw,
                                                 const float* __restrict__ fc,
                                                 const float* __restrict__ fs,
                                                 __bf16* __restrict__ qn,
                                                 __bf16* __restrict__ kn) {
  const int tid  = threadIdx.x;
  const int wid  = tid >> 6, lane = tid & 63;
  const int row  = blockIdx.x * 4 + wid;        // b*T + t
  const int b    = row >> 11, t = row & (T_ - 1);
  const float cs = fc[t * 64 + lane], sn = fs[t * 64 + lane];
  const float* base = qkv + (size_t)row * QKV_;

  #pragma unroll 2
  for (int h = 0; h < NH_; h++) {
    float2 ab = *(const float2*)(base + h * HD_ + 2 * lane);
    float oa = ab.x * cs - ab.y * sn;
    float ob = ab.x * sn + ab.y * cs;
    float ss = oa * oa + ob * ob;
    #pragma unroll
    for (int off = 32; off; off >>= 1) ss += __shfl_xor(ss, off);
    float rinv = rsqrtf(ss * (1.0f / HD_) + 1e-6f);
    bf16x2 o = { (__bf16)(oa * rinv * qw[2 * lane]), (__bf16)(ob * rinv * qw[2 * lane + 1]) };
    *(bf16x2*)&qn[(size_t)((b * NH_ + h) * T_ + t) * HD_ + 2 * lane] = o;
  }
  #pragma unroll 2
  for (int h = 0; h < KVH_; h++) {
    float2 ab = *(const float2*)(base + C_ + h * HD_ + 2 * lane);
    float oa = ab.x * cs - ab.y * sn;
    float ob = ab.x * sn + ab.y * cs;
    float ss = oa * oa + ob * ob;
    #pragma unroll
    for (int off = 32; off; off >>= 1) ss += __shfl_xor(ss, off);
    float rinv = rsqrtf(ss * (1.0f / HD_) + 1e-6f);
    bf16x2 o = { (__bf16)(oa * rinv * kw[2 * lane]), (__bf16)(ob * rinv * kw[2 * lane + 1]) };
    *(bf16x2*)&kn[(size_t)((b * KVH_ + h) * T_ + t) * HD_ + 2 * lane] = o;
  }
}

// ---------------- V transpose: qkv fp32 [t][d] -> vT bf16 [d][t], 64x64 LDS tiles ----
__global__ __launch_bounds__(256) void vtrans(const float* __restrict__ qkv,
                                              __bf16* __restrict__ vT) {
  __shared__ __bf16 L[64 * 68];
  const int tid = threadIdx.x;
  const int t0 = blockIdx.x * 64;
  const int d0 = blockIdx.y * 64;
  const int z  = blockIdx.z;            // b*KVH + hk
  const int b  = z >> 2, hk = z & 3;
  const int srcc = C_ + KVH_ * HD_ + hk * HD_ + d0;
  const int rr = tid >> 4, c4 = (tid & 15) * 4;
  #pragma unroll
  for (int i = 0; i < 4; i++) {
    int t = rr + i * 16;
    float4 f = *(const float4*)&qkv[(size_t)(b * T_ + t0 + t) * QKV_ + srcc + c4];
    bf16x4 o = { (__bf16)f.x, (__bf16)f.y, (__bf16)f.z, (__bf16)f.w };
    *(bf16x4*)&L[t * 68 + c4] = o;
  }
  __syncthreads();
  const int dr = tid >> 3, tc8 = (tid & 7) * 8;
  #pragma unroll
  for (int i = 0; i < 2; i++) {
    int d = dr + i * 32;
    bf16x8 ov;
    #pragma unroll
    for (int j = 0; j < 8; j++) ov[j] = L[(tc8 + j) * 68 + d];
    *(bf16x8*)&vT[(size_t)(z * HD_ + d0 + d) * T_ + t0 + tc8] = ov;
  }
}

// ---------------- causal flash attention, balanced + reg-prefetch pipelined ----------
// Grid x=16: block handles Q-tiles {31-x, x} (33 K-tiles each -> perfect balance).
// Single LDS K/V buffer (tiled [16x32] sub-blocks); tile it+1 prefetched into VGPRs
// during compute of tile it; 2 barriers/tile, global latency hidden under compute.
__device__ __forceinline__ void kv_prefetch(const __bf16* kbase, const __bf16* vbase,
                                            int kt0, int wid, int lane,
                                            bf16x8 kreg[4], bf16x8 vreg[4]) {
  const int r4 = lane >> 2, c8 = (lane & 3) * 8;
  const __bf16* kg = kbase + (size_t)(kt0 + wid * 16 + r4) * HD_ + c8;
  #pragma unroll
  for (int cb = 0; cb < 4; cb++) kreg[cb] = *(const bf16x8*)(kg + cb * 32);
  #pragma unroll
  for (int s = 0; s < 2; s++) {
    const __bf16* vg = vbase + (size_t)((wid * 2 + s) * 16 + r4) * T_ + kt0 + c8;
    #pragma unroll
    for (int cb = 0; cb < 2; cb++) vreg[s * 2 + cb] = *(const bf16x8*)(vg + cb * 32);
  }
}

__device__ __forceinline__ void kv_commit(__bf16* Ks, __bf16* Vs, int wid, int lane,
                                          const bf16x8 kreg[4], const bf16x8 vreg[4]) {
  #pragma unroll
  for (int cb = 0; cb < 4; cb++)
    *(bf16x8*)(Ks + wid * 2048 + cb * 512 + lane * 8) = kreg[cb];
  #pragma unroll
  for (int s = 0; s < 2; s++)
    #pragma unroll
    for (int cb = 0; cb < 2; cb++)
      *(bf16x8*)(Vs + (wid * 2 + s) * 1024 + cb * 512 + lane * 8) = vreg[s * 2 + cb];
}

__global__ __launch_bounds__(256) void flash(const __bf16* __restrict__ q,
                                             const __bf16* __restrict__ k,
                                             const __bf16* __restrict__ vT,
                                             __bf16* __restrict__ y) {
  __shared__ __align__(16) __bf16 Ks[64 * 128];   // tiles (rc,cb) of [16kt][32d]
  __shared__ __align__(16) __bf16 Vs[128 * 64];   // tiles (rc,cb) of [16d][32kt]
  __shared__ __align__(16) __bf16 Ps[4][16 * 72]; // per-wave P scratch (C->A), +8 pad
  const int tid = threadIdx.x;
  const int wid = tid >> 6, lane = tid & 63, quad = lane >> 4, r16 = lane & 15;
  const int h = blockIdx.y, b = blockIdx.z;
  const int hk = h >> 2;
  const __bf16* kbase = k  + (size_t)(b * KVH_ + hk) * T_ * HD_;
  const __bf16* vbase = vT + (size_t)(b * KVH_ + hk) * HD_ * T_;
  __bf16* Pw = Ps[wid];
  const float sc = 0.08838834764831845f;  // 1/sqrt(128)
  const float NEG = -__builtin_inff();
  bf16x8 ones;
  #pragma unroll
  for (int i = 0; i < 8; i++) ones[i] = (__bf16)1.0f;

  #pragma unroll 1
  for (int pass = 0; pass < 2; ++pass) {
    const int qt = pass ? blockIdx.x : (31 - blockIdx.x);
    const int nt = qt + 1;
    const int r0 = qt * 64 + wid * 16;

    const __bf16* qrow = q + ((size_t)(b * NH_ + h) * T_ + r0 + r16) * HD_;
    bf16x8 qf[4];
    #pragma unroll
    for (int kb = 0; kb < 4; kb++) qf[kb] = *(const bf16x8*)&qrow[kb * 32 + quad * 8];

    floatx4 o[8], ol = (floatx4){0.f, 0.f, 0.f, 0.f};
    #pragma unroll
    for (int j = 0; j < 8; j++) o[j] = (floatx4){0.f, 0.f, 0.f, 0.f};
    float m_r[4] = {NEG, NEG, NEG, NEG};

    bf16x8 kreg[4], vreg[4];
    kv_prefetch(kbase, vbase, 0, wid, lane, kreg, vreg);

    #pragma unroll 1
    for (int it = 0; it < nt; ++it) {
      __syncthreads();                          // all waves done reading previous tile
      kv_commit(Ks, Vs, wid, lane, kreg, vreg);
      __syncthreads();                          // tile it visible
      if (it + 1 < nt) kv_prefetch(kbase, vbase, (it + 1) * 64, wid, lane, kreg, vreg);

      const int kt0 = it * 64;
      floatx4 s[4];
      #pragma unroll
      for (int cb = 0; cb < 4; cb++) s[cb] = (floatx4){0.f, 0.f, 0.f, 0.f};
      #pragma unroll
      for (int kb = 0; kb < 4; kb++)
        #pragma unroll
        for (int cb = 0; cb < 4; cb++) {
          bf16x8 kf = *(const bf16x8*)&Ks[(cb * 4 + kb) * 512 + r16 * 32 + quad * 8];
          s[cb] = __builtin_amdgcn_mfma_f32_16x16x32_bf16(qf[kb], kf, s[cb], 0, 0, 0);
        }

      const bool last = (it == nt - 1);
      float alpha[4];
      #pragma unroll
      for (int reg = 0; reg < 4; reg++) {
        const int rowq = r0 + quad * 4 + reg;
        float v0 = s[0][reg] * sc, v1 = s[1][reg] * sc, v2 = s[2][reg] * sc, v3 = s[3][reg] * sc;
        if (last) {
          if (kt0 +      r16 > rowq) v0 = NEG;
          if (kt0 + 16 + r16 > rowq) v1 = NEG;
          if (kt0 + 32 + r16 > rowq) v2 = NEG;
          if (kt0 + 48 + r16 > rowq) v3 = NEG;
        }
        float mx = fmaxf(fmaxf(v0, v1), fmaxf(v2, v3));
        #pragma unroll
        for (int off = 8; off; off >>= 1) mx = fmaxf(mx, __shfl_xor(mx, off));
        float mnew = fmaxf(m_r[reg], mx);
        alpha[reg] = __expf(m_r[reg] - mnew);
        m_r[reg] = mnew;
        Pw[(quad * 4 + reg) * 72 +      r16] = (__bf16)__expf(v0 - mnew);
        Pw[(quad * 4 + reg) * 72 + 16 + r16] = (__bf16)__expf(v1 - mnew);
        Pw[(quad * 4 + reg) * 72 + 32 + r16] = (__bf16)__expf(v2 - mnew);
        Pw[(quad * 4 + reg) * 72 + 48 + r16] = (__bf16)__expf(v3 - mnew);
      }
      #pragma unroll
      for (int reg = 0; reg < 4; reg++) {
        ol[reg] *= alpha[reg];
        #pragma unroll
        for (int j = 0; j < 8; j++) o[j][reg] *= alpha[reg];
      }
      __asm__ volatile("" ::: "memory");        // wave-private P: writes before reads
      bf16x8 pf0 = *(const bf16x8*)&Pw[r16 * 72 + quad * 8];
      bf16x8 pf1 = *(const bf16x8*)&Pw[r16 * 72 + 32 + quad * 8];
      ol = __builtin_amdgcn_mfma_f32_16x16x32_bf16(pf0, ones, ol, 0, 0, 0);
      ol = __builtin_amdgcn_mfma_f32_16x16x32_bf16(pf1, ones, ol, 0, 0, 0);
      #pragma unroll
      for (int j = 0; j < 8; j++) {
        bf16x8 vf0 = *(const bf16x8*)&Vs[(j * 2 + 0) * 512 + r16 * 32 + quad * 8];
        bf16x8 vf1 = *(const bf16x8*)&Vs[(j * 2 + 1) * 512 + r16 * 32 + quad * 8];
        o[j] = __builtin_amdgcn_mfma_f32_16x16x32_bf16(pf0, vf0, o[j], 0, 0, 0);
        o[j] = __builtin_amdgcn_mfma_f32_16x16x32_bf16(pf1, vf1, o[j], 0, 0, 0);
      }
    }

    #pragma unroll
    for (int reg = 0; reg < 4; reg++) {
      int trow = r0 + quad * 4 + reg;
      float inv = 1.0f / ol[reg];
      __bf16* yr = y + ((size_t)(b * T_) + trow) * C_ + h * HD_;
      #pragma unroll
      for (int j = 0; j < 8; j++) yr[j * 16 + r16] = (__bf16)(o[j][reg] * inv);
    }
  }
}

extern "C" void kernel_launch(void* const* d_in, const int* in_sizes, int n_in,
                              void* d_out, int out_size, void* d_ws, size_t ws_size,
                              hipStream_t stream) {
  const float* x     = (const float*)d_in[0];
  const float* wqkv  = (const float*)d_in[1];
  const float* wproj = (const float*)d_in[2];
  const float* qw    = (const float*)d_in[3];
  const float* kw    = (const float*)d_in[4];
  const float* fc    = (const float*)d_in[5];
  const float* fs    = (const float*)d_in[6];
  float* out = (float*)d_out;

  char* w = (char*)d_ws;
  __bf16* xb     = (__bf16*)w; w += (size_t)M_ * C_ * 2;
  __bf16* wqkvb  = (__bf16*)w; w += (size_t)QKV_ * C_ * 2;
  __bf16* wprojb = (__bf16*)w; w += (size_t)C_ * C_ * 2;
  float*  qkv    = (float*)w;  w += (size_t)M_ * QKV_ * 4;
  __bf16* qn     = (__bf16*)w; w += (size_t)B_ * NH_ * T_ * HD_ * 2;
  __bf16* kn     = (__bf16*)w; w += (size_t)B_ * KVH_ * T_ * HD_ * 2;
  __bf16* vT     = (__bf16*)w; w += (size_t)B_ * KVH_ * T_ * HD_ * 2;
  __bf16* ybf    = (__bf16*)w; w += (size_t)M_ * C_ * 2;

  cvt_bf16<<<M_ * C_ / 4 / 256, 256, 0, stream>>>(x, xb, M_ * C_ / 4);
  cvt_bf16<<<QKV_ * C_ / 4 / 256, 256, 0, stream>>>(wqkv, wqkvb, QKV_ * C_ / 4);
  cvt_bf16<<<C_ * C_ / 4 / 256, 256, 0, stream>>>(wproj, wprojb, C_ * C_ / 4);

  gemm_bt<<<dim3(QKV_ / 128, M_ / 128), 256, 0, stream>>>(xb, wqkvb, qkv, QKV_, C_);
  rope_norm<<<M_ / 4, 256, 0, stream>>>(qkv, qw, kw, fc, fs, qn, kn);
  vtrans<<<dim3(T_ / 64, HD_ / 64, B_ * KVH_), 256, 0, stream>>>(qkv, vT);
  flash<<<dim3(16, NH_, B_), 256, 0, stream>>>(qn, kn, vT, ybf);
  gemm_bt<<<dim3(C_ / 128, M_ / 128), 256, 0, stream>>>(ybf, wprojb, out, C_, C_);
}